// Round 14
// baseline (220.954 us; speedup 1.0000x reference)
//
#include <hip/hip_runtime.h>
#include <hip/hip_bf16.h>

// MultiHeadAttention: x(8,256,32,32) -> qkv proj -> global-softmax attention -> out proj.
//   prep_all (R21/R26): fused preps, one launch. R26: all bf16 emits vectorized
//             to bf16x8 (fragment layout puts 8 consecutive aligned c at 8
//             contiguous bf16 -- (c&7) fastest axis). xt: 16 scalar stores ->
//             2 vec stores/thread; convert: f32x4-pair reads + 1 vec store.
//   proj_qkv: (x_t . w_in + b_in) * SCALE -> fragment-swizzled Qsw/Ksw/Vsw.
//             Barrier-free fragment-direct GEMM; depth-3 register pipeline
//             (R21/R22: depth-4 regressed ~6us -- regalloc squeeze; keep 3).
//   attn_fused: R11 schedule EXACTLY (vf loads, QK, exp+store, __syncthreads,
//             Qc prefetch, PV). R12-R14 lesson: ANY reorder of the global-load
//             issue pattern breaks sibling-block phase alignment -> shared Q/V
//             L2 reuse collapses (FETCH 49->56-62 MB, dur 88->117-123us). FROZEN.
//   g4 (gemm_nt mode 5) + reduce_out: NON-ATOMIC split-K=4 in SEPARATE launches.
//             R20: atomic RMW = +25us cross-XCD line ping-pong. R23: fused
//             reduction via __threadfence = +70us (device fence -> L2 writeback
//             per block on non-coherent XCD L2s). Kernel boundary is the only
//             cheap cross-XCD handoff. R24: NT hints neutral (within noise).
// Session noise band ~+/-3us (R22=215.1, R25 identical source=218.1).
// Global softmax: att ~ N(0,0.17^2) -> exp() without max-subtraction is safe.
// Fragment layouts (32x32x16, verified R7-R10): A/B lane: row=lane&31, k=(lane>>5)*8+j;
//   C/D: col=lane&31, row=(reg&3)+8*(reg>>2)+4*(lane>>5).
// Frag buffers: elem(rb,k-frag) tile = 512 bf16 contiguous; within: (row&31, k8)*8+(k&7).

typedef __bf16 bf16x8 __attribute__((ext_vector_type(8)));
typedef __bf16 bf16x4 __attribute__((ext_vector_type(4)));
typedef float f32x4 __attribute__((ext_vector_type(4)));
typedef float f32x16 __attribute__((ext_vector_type(16)));
typedef __hip_bfloat16 bf16;

__device__ __forceinline__ void async_copy16(const void* g, void* s) {
    __builtin_amdgcn_global_load_lds(
        (const __attribute__((address_space(1))) unsigned int*)g,
        (__attribute__((address_space(3))) unsigned int*)s, 16, 0, 0);
}

__device__ __forceinline__ bf16x8 scale8(bf16x8 v, float s) {
    bf16x8 r;
#pragma unroll
    for (int e = 0; e < 8; ++e) r[e] = (__bf16)((float)v[e] * s);
    return r;
}

// ---------------------------------------------------------------------------
// QKV projection, fragment-direct. Block = 128l x 128o; grid 3072 (XCD n = b&7).
// Per wave (2x2 of 64x64): 16 k-steps x 4 MFMA(32x32x16), operands global-coalesced,
// depth-3 register ping-pong, NO barriers until the epilogue swizzled emit.
__global__ __launch_bounds__(256)
void proj_qkv(const bf16* __restrict__ Axw, const bf16* __restrict__ Wsw,
              const float* __restrict__ bias, float scale,
              bf16* __restrict__ outQ, bf16* __restrict__ outK, bf16* __restrict__ outV)
{
    __shared__ __align__(16) bf16 smem[16384];

    const int tid  = threadIdx.x;
    const int wave = tid >> 6, lane = tid & 63;
    const int l31  = lane & 31, hw = lane >> 5;

    const int b  = blockIdx.x;
    const int n  = b & 7;                 // XCD affinity: one batch image per XCD
    const int s  = b >> 3;                // [0,384)
    const int ht = s / 48;
    const int r_ = s % 48;
    const int part = r_ % 6;              // 0,1=Q; 2,3=K; 4,5=V (d-halves)
    const int lt   = r_ / 6;              // l-tile of 128
    const int nh = n * 8 + ht;
    const int o0 = ht * 768 + part * 128; // global o column base
    const int d0 = (part & 1) * 128;

    const int wl = wave & 1, wo = wave >> 1;

    const bf16* Ap0 = Axw + ((long)(n * 32 + lt * 4 + wl * 2) * 16) * 512 + lane * 8;
    const bf16* Ap1 = Ap0 + 16 * 512;
    const bf16* Bp0 = Wsw + ((long)(ht * 24 + part * 4 + wo * 2) * 16) * 512 + lane * 8;
    const bf16* Bp1 = Bp0 + 16 * 512;

    bf16x8 Af[3][2], Bf[3][2];
#pragma unroll
    for (int p = 0; p < 3; ++p) {
        Af[p][0] = *(const bf16x8*)(Ap0 + p * 512);
        Af[p][1] = *(const bf16x8*)(Ap1 + p * 512);
        Bf[p][0] = *(const bf16x8*)(Bp0 + p * 512);
        Bf[p][1] = *(const bf16x8*)(Bp1 + p * 512);
    }

    f32x16 acc[2][2] = {};
#pragma unroll
    for (int k = 0; k < 16; ++k) {
        const int st = k % 3;
#pragma unroll
        for (int i = 0; i < 2; ++i)
#pragma unroll
            for (int j = 0; j < 2; ++j)
                acc[i][j] = __builtin_amdgcn_mfma_f32_32x32x16_bf16(
                    Af[st][i], Bf[st][j], acc[i][j], 0, 0, 0);
        if (k + 3 < 16) {
            Af[st][0] = *(const bf16x8*)(Ap0 + (k + 3) * 512);
            Af[st][1] = *(const bf16x8*)(Ap1 + (k + 3) * 512);
            Bf[st][0] = *(const bf16x8*)(Bp0 + (k + 3) * 512);
            Bf[st][1] = *(const bf16x8*)(Bp1 + (k + 3) * 512);
        }
    }

    // Epilogue: bias+scale, stage 128x128 swizzled, one barrier, b128 stores.
    float bv[2];
#pragma unroll
    for (int j = 0; j < 2; ++j) bv[j] = bias[o0 + wo * 64 + j * 32 + l31];

    if (part < 4) {
#pragma unroll
        for (int i = 0; i < 2; ++i)
#pragma unroll
            for (int j = 0; j < 2; ++j)
#pragma unroll
                for (int r = 0; r < 16; ++r) {
                    const int row = wl * 64 + i * 32 + (r & 3) + 8 * (r >> 2) + 4 * hw; // l
                    const int col = wo * 64 + j * 32 + l31;                              // d
                    const float v = (acc[i][j][r] + bv[j]) * scale;
                    const int c32 = col >> 3;
                    const int slot = (c32 & 8) | ((c32 & 7) ^ (row & 7));
                    smem[row * 128 + slot * 8 + (col & 7)] = __float2bfloat16(v);
                }
        __syncthreads();
        bf16* dst = (part < 2) ? outQ : outK;
#pragma unroll
        for (int k = 0; k < 8; ++k) {
            const int flat = k * 256 + tid;
            const int seg  = flat >> 6, ln = flat & 63;
            const int lb   = seg >> 3, wloc = seg & 7;
            const int row  = lb * 32 + (ln & 31);
            const int c32  = wloc * 2 + (ln >> 5);
            const int slot = (c32 & 8) | ((c32 & 7) ^ (row & 7));
            const f32x4 val = *(const f32x4*)(smem + row * 128 + slot * 8);
            const long addr = ((long)(nh * 32 + lt * 4 + lb) * 16 + (d0 >> 4) + wloc) * 512 + ln * 8;
            *(f32x4*)(dst + addr) = val;
        }
    } else {
        // V: stage transposed (rows d, chunks of l).
#pragma unroll
        for (int i = 0; i < 2; ++i)
#pragma unroll
            for (int j = 0; j < 2; ++j)
#pragma unroll
                for (int r = 0; r < 16; ++r) {
                    const int row = wl * 64 + i * 32 + (r & 3) + 8 * (r >> 2) + 4 * hw; // l
                    const int col = wo * 64 + j * 32 + l31;                              // d
                    const float v = (acc[i][j][r] + bv[j]) * scale;
                    const int rc = row >> 3;
                    const int slotT = (rc & 8) | ((rc & 7) ^ (col & 7));
                    smem[col * 128 + slotT * 8 + (row & 7)] = __float2bfloat16(v);
                }
        __syncthreads();
#pragma unroll
        for (int k = 0; k < 8; ++k) {
            const int flat = k * 256 + tid;
            const int seg  = flat >> 6, ln = flat & 63;
            const int kwl  = seg >> 2, g2l = seg & 3;
            const int dl   = g2l * 32 + (ln & 31);
            const int lc   = kwl * 2 + (ln >> 5);
            const int slotT = (lc & 8) | ((lc & 7) ^ (dl & 7));
            const f32x4 val = *(const f32x4*)(smem + dl * 128 + slotT * 8);
            const long addr = ((long)(nh * 64 + lt * 8 + kwl) * 8 + (d0 >> 5) + g2l) * 512 + ln * 8;
            *(f32x4*)(outV + addr) = val;
        }
    }
}

// ---------------------------------------------------------------------------
// Generic NT bf16 GEMM (kept for g4 only). 128x128 tile, BK=64, m97+R4 structure.
// mode 3: C=f32, acc + bias[row]
// mode 4: split-K atomic: atomicAdd(C, acc + (zh==0 ? bias[row] : 0))
// mode 5: split-K NON-atomic: plain store of acc to per-zh partial buffer
//         (bias applied later in reduce_out). B scaled by
//         1/Zp[zn*8 + zh*hperz + kt/4] during staging (hperz = 8/H).
__global__ __launch_bounds__(256)
void gemm_nt(const bf16* __restrict__ A, const bf16* __restrict__ B, void* __restrict__ Cvoid,
             int M, int N, int K, int lda, int ldb, int ldc,
             long asn, long ash, long bsn, long bsh, long csn, long csh,
             int H, int mode, const float* __restrict__ bias, const float* __restrict__ Zp,
             float scale)
{
    __shared__ __align__(16) bf16 smem[17408];
    bf16* Alds = smem;
    bf16* Blds = smem + 8192;

    const int tid  = threadIdx.x;
    const int wave = tid >> 6;
    const int lane = tid & 63;
    const int z  = blockIdx.z;
    const int zn = z / H, zh = z % H;
    const int hperz = 8 / H;

    const bf16* Ab = A + zn * asn + zh * ash;
    const bf16* Bb = B + zn * bsn + zh * bsh;

    const long tM = (long)blockIdx.y * 128;
    const long tN = (long)blockIdx.x * 128;

    const int wr   = (wave >> 1) * 64;
    const int wc   = (wave & 1) * 64;
    const int l15  = lane & 15;
    const int quad = lane >> 4;

    f32x4 acc[4][4] = {};

    const int kiters = K >> 6;
    const bool regB = (mode >= 4);

#pragma unroll
    for (int i = 0; i < 4; ++i) {
        const int flat = i * 256 + tid;
        const int row  = flat >> 3;
        const int kcs  = (flat & 7) ^ (row & 7);
        async_copy16(Ab + (tM + row) * (long)lda + kcs * 8,
                     (char*)Alds + (long)(i * 256 + wave * 64) * 16);
        if (!regB) {
            async_copy16(Bb + (tN + row) * (long)ldb + kcs * 8,
                         (char*)Blds + (long)(i * 256 + wave * 64) * 16);
        }
    }
    if (regB) {
        const float zi0 = 1.0f / Zp[zn * 8 + zh * hperz];
#pragma unroll
        for (int i = 0; i < 4; ++i) {
            const int flat = i * 256 + tid;
            const int row  = flat >> 3;
            const int kcs  = (flat & 7) ^ (row & 7);
            bf16x8 bv = *(const bf16x8*)(Bb + (tN + row) * (long)ldb + kcs * 8);
            *(bf16x8*)((char*)Blds + (long)flat * 16) = scale8(bv, zi0);
        }
    }

    bf16x8 pfA[4], pfB[4];
    for (int kt = 0; kt < kiters; ++kt) {
        __syncthreads();
        const bool has_next = (kt + 1 < kiters);
        float zin = 1.0f;
        if (has_next) {
            const long kof = (long)(kt + 1) * 64;
            if (regB) zin = 1.0f / Zp[zn * 8 + zh * hperz + ((kt + 1) >> 2)];
#pragma unroll
            for (int i = 0; i < 4; ++i) {
                const int flat = i * 256 + tid;
                const int row  = flat >> 3;
                const int kcs  = (flat & 7) ^ (row & 7);
                pfA[i] = *(const bf16x8*)(Ab + (tM + row) * (long)lda + kof + kcs * 8);
                pfB[i] = *(const bf16x8*)(Bb + (tN + row) * (long)ldb + kof + kcs * 8);
            }
        }
#pragma unroll
        for (int kk = 0; kk < 2; ++kk) {
            bf16x8 af[4], bfv[4];
#pragma unroll
            for (int i = 0; i < 4; ++i) {
                const int r = wr + i * 16 + l15;
                af[i] = *(const bf16x8*)(Alds + r * 64 + ((kk * 4 + quad) ^ (r & 7)) * 8);
            }
#pragma unroll
            for (int j = 0; j < 4; ++j) {
                const int r = wc + j * 16 + l15;
                bfv[j] = *(const bf16x8*)(Blds + r * 64 + ((kk * 4 + quad) ^ (r & 7)) * 8);
            }
#pragma unroll
            for (int i = 0; i < 4; ++i)
#pragma unroll
                for (int j = 0; j < 4; ++j)
                    acc[i][j] = __builtin_amdgcn_mfma_f32_16x16x32_bf16(af[i], bfv[j], acc[i][j], 0, 0, 0);
        }
        if (has_next) {
            __builtin_amdgcn_sched_barrier(0);
            __builtin_amdgcn_s_barrier();
            __builtin_amdgcn_sched_barrier(0);
#pragma unroll
            for (int i = 0; i < 4; ++i) {
                const int flat = i * 256 + tid;
                *(bf16x8*)((char*)Alds + (long)flat * 16) = pfA[i];
                *(bf16x8*)((char*)Blds + (long)flat * 16) = regB ? scale8(pfB[i], zin) : pfB[i];
            }
        }
    }

    float* C = (float*)Cvoid + zn * csn + zh * csh;
#pragma unroll
    for (int i = 0; i < 4; ++i)
#pragma unroll
        for (int j = 0; j < 4; ++j)
#pragma unroll
            for (int r = 0; r < 4; ++r) {
                const long row = tM + wr + i * 16 + quad * 4 + r;
                const long col = tN + wc + j * 16 + l15;
                if (mode == 5) {
                    C[row * (long)ldc + col] = acc[i][j][r];
                } else if (mode == 4) {
                    const float v = acc[i][j][r] + (zh == 0 ? bias[row] : 0.0f);
                    atomicAdd(&C[row * (long)ldc + col], v);
                } else {
                    C[row * (long)ldc + col] = acc[i][j][r] + bias[row];
                }
            }
}

// ---------------------------------------------------------------------------
// reduce_out (R20): out[n][c][l] = sum_{zh<4} Pt[zh][n][c][l] + b_out[c].
// Elementwise f32x4; 524288 vec4 elements; 40 MB traffic (~7us HBM-bound).
__global__ __launch_bounds__(256)
void reduce_out(const float* __restrict__ Pt, const float* __restrict__ bias,
                float* __restrict__ out)
{
    const int idx = blockIdx.x * 256 + threadIdx.x;       // [0, 524288)
    const int c   = (idx >> 8) & 255;                     // (idx*4 >> 10) & 255
    f32x4 s = ((const f32x4*)Pt)[idx];
    s += ((const f32x4*)(Pt + 2097152))[idx];
    s += ((const f32x4*)(Pt + 4194304))[idx];
    s += ((const f32x4*)(Pt + 6291456))[idx];
    const float b = bias[c];
    s[0] += b; s[1] += b; s[2] += b; s[3] += b;
    ((f32x4*)out)[idx] = s;
}

// ---------------------------------------------------------------------------
// Fused attention v6 (R11 schedule, verbatim). Block = (64-key m-tile, nh); grid 1024.
// Per lt: vf loads, QK MFMAs, exp+P store, __syncthreads, Qc(lt+1) prefetch, PV.
// DO NOT reorder the global loads relative to the barrier (R12-R14: +30-40% dur).
__global__ __launch_bounds__(256, 2)
void attn_fused(const bf16* __restrict__ Qsw, const bf16* __restrict__ Ksw,
                const bf16* __restrict__ Vsw, bf16* __restrict__ out_tt,
                float* __restrict__ Z)
{
    __shared__ __align__(16) bf16 smem[16904];
    bf16* Ps  = smem;
    float* Zs = (float*)(smem + 16896);

    const int tid  = threadIdx.x;
    const int wave = tid >> 6, lane = tid & 63;
    const int l31  = lane & 31, hw = lane >> 5;

    const int b   = blockIdx.x;
    const int xcd = b & 7, s = b >> 3;
    const int nh  = xcd * 8 + (s >> 4);
    const int mt  = s & 15;
    const int n   = nh >> 3, h = nh & 7;
    const long m0 = (long)mt * 64;

    const int wl = wave & 1, wm = wave >> 1;

    bf16x8 Kf[16];
    {
        const bf16* kb = Ksw + ((long)(nh * 32 + mt * 2 + wm) * 16) * 512 + lane * 8;
#pragma unroll
        for (int w = 0; w < 16; ++w)
            Kf[w] = *(const bf16x8*)(kb + w * 512);
    }
    bf16x8 Qc[16];
    {
        const bf16* qb = Qsw + ((long)(nh * 32 + wl) * 16) * 512 + lane * 8;
#pragma unroll
        for (int w = 0; w < 16; ++w)
            Qc[w] = *(const bf16x8*)(qb + w * 512);
    }

    f32x16 accO[2][2] = {};
    float zsum = 0.0f;

    for (int lt = 0; lt < 16; ++lt) {
        bf16x8 vf[4][2];
#pragma unroll
        for (int kw = 0; kw < 4; ++kw)
#pragma unroll
            for (int dt = 0; dt < 2; ++dt)
                vf[kw][dt] = *(const bf16x8*)(
                    Vsw + ((long)(nh * 64 + lt * 4 + kw) * 8 + wave * 2 + dt) * 512 + lane * 8);

        f32x16 a0 = {}, a1 = {};
#pragma unroll
        for (int w = 0; w < 16; w += 2) {
            a0 = __builtin_amdgcn_mfma_f32_32x32x16_bf16(Qc[w], Kf[w], a0, 0, 0, 0);
            a1 = __builtin_amdgcn_mfma_f32_32x32x16_bf16(Qc[w + 1], Kf[w + 1], a1, 0, 0, 0);
        }

        bf16* Pb = Ps + (lt & 1) * 6144;
#pragma unroll
        for (int g = 0; g < 4; ++g) {
            bf16x4 pk;
#pragma unroll
            for (int e = 0; e < 4; ++e) {
                const float v = __expf(a0[g * 4 + e] + a1[g * 4 + e]);
                zsum += v;
                pk[e] = (__bf16)v;
            }
            const int l  = wl * 32 + 4 * hw + 8 * g;
            const int kw = l >> 4, off = l & 15;
            *(bf16x4*)(Pb + kw * 1536 + (wm * 32 + l31) * 24 + off) = pk;
        }

        __syncthreads();

        if (lt < 15) {
            const bf16* qn = Qsw + ((long)(nh * 32 + (lt + 1) * 2 + wl) * 16) * 512 + lane * 8;
#pragma unroll
            for (int w = 0; w < 16; ++w)
                Qc[w] = *(const bf16x8*)(qn + w * 512);
        }

#pragma unroll
        for (int kw = 0; kw < 4; ++kw) {
            bf16x8 pf[2];
#pragma unroll
            for (int mh = 0; mh < 2; ++mh)
                pf[mh] = *(const bf16x8*)(Pb + kw * 1536 + (mh * 32 + l31) * 24 + hw * 8);
#pragma unroll
            for (int mh = 0; mh < 2; ++mh)
#pragma unroll
                for (int dt = 0; dt < 2; ++dt)
                    accO[mh][dt] = __builtin_amdgcn_mfma_f32_32x32x16_bf16(
                        pf[mh], vf[kw][dt], accO[mh][dt], 0, 0, 0);
        }
    }

    __syncthreads();

#pragma unroll
    for (int o = 32; o > 0; o >>= 1) zsum += __shfl_down(zsum, o);
    if (lane == 0) Zs[wave] = zsum;

    bf16* Cs = smem;
#pragma unroll
    for (int mh = 0; mh < 2; ++mh)
#pragma unroll
        for (int dt = 0; dt < 2; ++dt)
#pragma unroll
            for (int r = 0; r < 16; ++r) {
                const int m = mh * 32 + (r & 3) + 8 * (r >> 2) + 4 * hw;
                const int d = wave * 64 + dt * 32 + l31;
                Cs[m * 264 + d] = __float2bfloat16(accO[mh][dt][r]);
            }
    __syncthreads();
    if (tid == 0) atomicAdd(Z + nh, (Zs[0] + Zs[1]) + (Zs[2] + Zs[3]));

    bf16* Ob = out_tt + (long)n * 2097152 + m0 * 2048 + h * 256;
#pragma unroll
    for (int k = 0; k < 8; ++k) {
        const int flat = k * 256 + tid;
        const int row  = flat >> 5;
        const int c    = flat & 31;
        const f32x4 val = *(const f32x4*)((const char*)Cs + row * 528 + c * 16);
        *(f32x4*)((char*)(Ob + (long)row * 2048) + c * 16) = val;
    }
}

// ---------------------------------------------------------------------------
// prep_all (R26): fused prep, vectorized emits. Blocks [0,512): x transpose ->
// Axw fragment layout; per thread 2 bf16x8 stores (was 16 scalar). Blocks
// [512,1536): w_in -> Wsw (one 8-c group per thread: 2x f32x4 read + 1 bf16x8
// store), w_out -> linear bf16 (8 elems/thread), Z zeroing.
// Fragment layout fact: 8 consecutive aligned c -> 8 contiguous bf16 ((c&7) is
// the fastest axis; c>>4 and (c>>3)&1 constant within the group).
__global__ void prep_all(const float* __restrict__ x, const float* __restrict__ w_in,
                         const float* __restrict__ w_out, bf16* __restrict__ Axw,
                         bf16* __restrict__ Wsw, bf16* __restrict__ w_out_b,
                         float* __restrict__ Z)
{
    __shared__ float tile[64][65];
    const int t = threadIdx.x;

    if (blockIdx.x < 512) {
        // ---- prep_xt ----
        const int bid = blockIdx.x;
        const int n = bid >> 6;
        const int b = bid & 63;
        const int ct = b & 3, lt = b >> 2;
        const float* xp = x + (long)n * 256 * 1024;
#pragma unroll
        for (int i = 0; i < 16; ++i) {
            const int flat = i * 256 + t;
            const int cl = flat >> 6, ll = flat & 63;
            tile[cl][ll] = xp[(long)(ct * 64 + cl) * 1024 + lt * 64 + ll];
        }
        __syncthreads();
        // 512 items = (lr in [0,64)) x (cg in [0,8)); each emits one bf16x8.
#pragma unroll
        for (int i = 0; i < 2; ++i) {
            const int item = i * 256 + t;
            const int lr = item >> 3, cg = item & 7;
            const int l  = lt * 64 + lr;
            const int c0 = ct * 64 + cg * 8;
            union { bf16 h[8]; bf16x8 v; } u;
#pragma unroll
            for (int e = 0; e < 8; ++e)
                u.h[e] = __float2bfloat16(tile[cg * 8 + e][lr]);
            const long addr = ((long)((n * 32 + (l >> 5)) * 16 + (c0 >> 4))) * 512
                            + ((l & 31) + 32 * ((c0 >> 3) & 1)) * 8;
            *(bf16x8*)(Axw + addr) = u.v;
        }
    } else {
        // ---- prep_convert ----
        const int cb  = blockIdx.x - 512;                 // [0, 1024)
        const int gid = cb * 256 + t;                     // [0, 262144)
        if (cb == 0 && t < 64) Z[t] = 0.0f;
        if (gid < 196608) {
            // Wsw: one (o, 8-c group). 6144 o x 32 groups = 196608.
            const int o  = gid >> 5;
            const int c0 = (gid & 31) * 8;
            const float* src = w_in + (long)o * 256 + c0;
            const f32x4 a = *(const f32x4*)(src);
            const f32x4 c = *(const f32x4*)(src + 4);
            union { bf16 h[8]; bf16x8 v; } u;
#pragma unroll
            for (int e = 0; e < 4; ++e) {
                u.h[e]     = __float2bfloat16(a[e]);
                u.h[e + 4] = __float2bfloat16(c[e]);
            }
            const long addr = ((long)((o >> 5) * 16 + (c0 >> 4))) * 512
                            + ((o & 31) + 32 * ((c0 >> 3) & 1)) * 8;
            *(bf16x8*)(Wsw + addr) = u.v;
        } else {
            // w_out_b: linear, 8 elems per thread. 65536 groups.
            const long g = gid - 196608;                  // [0, 65536)
            const float* src = w_out + g * 8;
            const f32x4 a = *(const f32x4*)(src);
            const f32x4 c = *(const f32x4*)(src + 4);
            union { bf16 h[8]; bf16x8 v; } u;
#pragma unroll
            for (int e = 0; e < 4; ++e) {
                u.h[e]     = __float2bfloat16(a[e]);
                u.h[e + 4] = __float2bfloat16(c[e]);
            }
            *(bf16x8*)(w_out_b + g * 8) = u.v;
        }
    }
}

extern "C" void kernel_launch(void* const* d_in, const int* in_sizes, int n_in,
                              void* d_out, int out_size, void* d_ws, size_t ws_size,
                              hipStream_t stream)
{
    const float* x     = (const float*)d_in[0];
    const float* w_in  = (const float*)d_in[1];
    const float* b_in  = (const float*)d_in[2];
    const float* w_out = (const float*)d_in[3];
    const float* b_out = (const float*)d_in[4];
    float* out = (float*)d_out;

    const float SCALE = 0.10416666666666667f;     // 1/16 * sqrt(6400/2304) = 5/48

    char* p = (char*)d_ws;
    bf16* Qsw     = (bf16*)p;  p += 33554432;     // fragment-swizzled Q
    bf16* Ksw     = (bf16*)p;  p += 33554432;     // fragment-swizzled K
    bf16* Vsw     = (bf16*)p;  p += 33554432;     // fragment-swizzled V (transposed)
    bf16* out_tt  = (bf16*)p;  p += 33554432;     // (8, 1024, 2048) bf16 (unnormalized)
    bf16* Axw     = (bf16*)p;  p += 4194304;      // x_t fragment layout
    bf16* Wsw     = (bf16*)p;  p += 3145728;      // w_in fragment layout
    bf16* w_out_b = (bf16*)p;  p += 1048576;      // (256, 2048) bf16 linear
    float* Z      = (float*)p; p += 256;          // 64 softmax denominators
    float* Pt     = (float*)p; p += 33554432;     // 4 x (8,256,1024) f32 split-K partials

    // fused preps: xt blocks [0,512) + convert blocks [512,1536).
    prep_all<<<1536, 256, 0, stream>>>(x, w_in, w_out, Axw, Wsw, w_out_b, Z);

    // g1: fragment-direct projection, 3072 blocks (8n x 8ht x 6part x 8lt).
    proj_qkv<<<3072, 256, 0, stream>>>(Axw, Wsw, b_in, SCALE, Qsw, Ksw, Vsw);

    // fused attention (1D grid, XCD-swizzled)
    attn_fused<<<1024, 256, 0, stream>>>(Qsw, Ksw, Vsw, out_tt, Z);

    // g4: split-K=4 NON-atomic (R20). z = n*4 + zh, K=512/chunk, kiters=8,
    // 512 blocks (2 blocks/CU). Partials: Pt[zh][n][256][1024] f32.
    gemm_nt<<<dim3(8, 2, 32), 256, 0, stream>>>(
        w_out_b, out_tt, Pt,
        256, 1024, 512, 2048, 2048, 1024,
        0, 512, 1024L * 2048, 512, 262144, 2097152,
        4, 5, b_out, Z, 1.0f);

    // sum 4 partials + bias -> out (524288 f32x4, 2048 blocks).
    reduce_out<<<2048, 256, 0, stream>>>(Pt, b_out, out);
}

// Round 15
// 212.749 us; speedup vs baseline: 1.0386x; 1.0386x over previous
//
#include <hip/hip_runtime.h>
#include <hip/hip_bf16.h>

// MultiHeadAttention: x(8,256,32,32) -> qkv proj -> global-softmax attention -> out proj.
// FINAL (R27 = R22 verbatim, session best 215.1us; noise band +/-3us).
//   prep_all: fused prep_convert + prep_xt (one launch; xt blocks 0-511,
//             convert blocks 512-2559). R26 vectorization was neutral (prep is
//             launch/HBM-floor bound) -- keep the twice-measured R22 source.
//   proj_qkv: (x_t . w_in + b_in) * SCALE -> fragment-swizzled Qsw/Ksw/Vsw.
//             Barrier-free fragment-direct GEMM; depth-3 register pipeline
//             (depth-4: +6us regalloc squeeze R21; VGPR cap: +24us spill R17).
//   attn_fused: R11 schedule EXACTLY (vf loads, QK, exp+store, __syncthreads,
//             Qc prefetch, PV). R12-R14: ANY reorder of the global-load issue
//             pattern vs the barrier breaks sibling-block phase alignment ->
//             shared Q/V L2 reuse collapses (FETCH 49->56-62MB, 88->117-123us).
//   g4 (gemm_nt mode 5) + reduce_out: NON-ATOMIC split-K=4, SEPARATE launches.
//             R16/R20: atomic RMW = +25us cross-XCD line ping-pong.
//             R23: fused reduction via __threadfence = +70us (device fence ->
//             per-block L2 writeback on non-coherent XCD L2s; MfmaUtil 3.2%).
//             The kernel boundary is the only cheap cross-XCD handoff.
//             R24: NT hints on Pt neutral.
// Global softmax: att ~ N(0,0.17^2) -> exp() without max-subtraction is safe.
// Fragment layouts (32x32x16, verified R7-R10): A/B lane: row=lane&31, k=(lane>>5)*8+j;
//   C/D: col=lane&31, row=(reg&3)+8*(reg>>2)+4*(lane>>5).
// Frag buffers: elem(rb,k-frag) tile = 512 bf16 contiguous; within: (row&31, k8)*8+(k&7).

typedef __bf16 bf16x8 __attribute__((ext_vector_type(8)));
typedef __bf16 bf16x4 __attribute__((ext_vector_type(4)));
typedef float f32x4 __attribute__((ext_vector_type(4)));
typedef float f32x16 __attribute__((ext_vector_type(16)));
typedef __hip_bfloat16 bf16;

__device__ __forceinline__ void async_copy16(const void* g, void* s) {
    __builtin_amdgcn_global_load_lds(
        (const __attribute__((address_space(1))) unsigned int*)g,
        (__attribute__((address_space(3))) unsigned int*)s, 16, 0, 0);
}

__device__ __forceinline__ bf16x8 scale8(bf16x8 v, float s) {
    bf16x8 r;
#pragma unroll
    for (int e = 0; e < 8; ++e) r[e] = (__bf16)((float)v[e] * s);
    return r;
}

// ---------------------------------------------------------------------------
// QKV projection, fragment-direct. Block = 128l x 128o; grid 3072 (XCD n = b&7).
// Per wave (2x2 of 64x64): 16 k-steps x 4 MFMA(32x32x16), operands global-coalesced,
// depth-3 register ping-pong, NO barriers until the epilogue swizzled emit.
__global__ __launch_bounds__(256)
void proj_qkv(const bf16* __restrict__ Axw, const bf16* __restrict__ Wsw,
              const float* __restrict__ bias, float scale,
              bf16* __restrict__ outQ, bf16* __restrict__ outK, bf16* __restrict__ outV)
{
    __shared__ __align__(16) bf16 smem[16384];

    const int tid  = threadIdx.x;
    const int wave = tid >> 6, lane = tid & 63;
    const int l31  = lane & 31, hw = lane >> 5;

    const int b  = blockIdx.x;
    const int n  = b & 7;                 // XCD affinity: one batch image per XCD
    const int s  = b >> 3;                // [0,384)
    const int ht = s / 48;
    const int r_ = s % 48;
    const int part = r_ % 6;              // 0,1=Q; 2,3=K; 4,5=V (d-halves)
    const int lt   = r_ / 6;              // l-tile of 128
    const int nh = n * 8 + ht;
    const int o0 = ht * 768 + part * 128; // global o column base
    const int d0 = (part & 1) * 128;

    const int wl = wave & 1, wo = wave >> 1;

    const bf16* Ap0 = Axw + ((long)(n * 32 + lt * 4 + wl * 2) * 16) * 512 + lane * 8;
    const bf16* Ap1 = Ap0 + 16 * 512;
    const bf16* Bp0 = Wsw + ((long)(ht * 24 + part * 4 + wo * 2) * 16) * 512 + lane * 8;
    const bf16* Bp1 = Bp0 + 16 * 512;

    bf16x8 Af[3][2], Bf[3][2];
#pragma unroll
    for (int p = 0; p < 3; ++p) {
        Af[p][0] = *(const bf16x8*)(Ap0 + p * 512);
        Af[p][1] = *(const bf16x8*)(Ap1 + p * 512);
        Bf[p][0] = *(const bf16x8*)(Bp0 + p * 512);
        Bf[p][1] = *(const bf16x8*)(Bp1 + p * 512);
    }

    f32x16 acc[2][2] = {};
#pragma unroll
    for (int k = 0; k < 16; ++k) {
        const int st = k % 3;
#pragma unroll
        for (int i = 0; i < 2; ++i)
#pragma unroll
            for (int j = 0; j < 2; ++j)
                acc[i][j] = __builtin_amdgcn_mfma_f32_32x32x16_bf16(
                    Af[st][i], Bf[st][j], acc[i][j], 0, 0, 0);
        if (k + 3 < 16) {
            Af[st][0] = *(const bf16x8*)(Ap0 + (k + 3) * 512);
            Af[st][1] = *(const bf16x8*)(Ap1 + (k + 3) * 512);
            Bf[st][0] = *(const bf16x8*)(Bp0 + (k + 3) * 512);
            Bf[st][1] = *(const bf16x8*)(Bp1 + (k + 3) * 512);
        }
    }

    // Epilogue: bias+scale, stage 128x128 swizzled, one barrier, b128 stores.
    float bv[2];
#pragma unroll
    for (int j = 0; j < 2; ++j) bv[j] = bias[o0 + wo * 64 + j * 32 + l31];

    if (part < 4) {
#pragma unroll
        for (int i = 0; i < 2; ++i)
#pragma unroll
            for (int j = 0; j < 2; ++j)
#pragma unroll
                for (int r = 0; r < 16; ++r) {
                    const int row = wl * 64 + i * 32 + (r & 3) + 8 * (r >> 2) + 4 * hw; // l
                    const int col = wo * 64 + j * 32 + l31;                              // d
                    const float v = (acc[i][j][r] + bv[j]) * scale;
                    const int c32 = col >> 3;
                    const int slot = (c32 & 8) | ((c32 & 7) ^ (row & 7));
                    smem[row * 128 + slot * 8 + (col & 7)] = __float2bfloat16(v);
                }
        __syncthreads();
        bf16* dst = (part < 2) ? outQ : outK;
#pragma unroll
        for (int k = 0; k < 8; ++k) {
            const int flat = k * 256 + tid;
            const int seg  = flat >> 6, ln = flat & 63;
            const int lb   = seg >> 3, wloc = seg & 7;
            const int row  = lb * 32 + (ln & 31);
            const int c32  = wloc * 2 + (ln >> 5);
            const int slot = (c32 & 8) | ((c32 & 7) ^ (row & 7));
            const f32x4 val = *(const f32x4*)(smem + row * 128 + slot * 8);
            const long addr = ((long)(nh * 32 + lt * 4 + lb) * 16 + (d0 >> 4) + wloc) * 512 + ln * 8;
            *(f32x4*)(dst + addr) = val;
        }
    } else {
        // V: stage transposed (rows d, chunks of l).
#pragma unroll
        for (int i = 0; i < 2; ++i)
#pragma unroll
            for (int j = 0; j < 2; ++j)
#pragma unroll
                for (int r = 0; r < 16; ++r) {
                    const int row = wl * 64 + i * 32 + (r & 3) + 8 * (r >> 2) + 4 * hw; // l
                    const int col = wo * 64 + j * 32 + l31;                              // d
                    const float v = (acc[i][j][r] + bv[j]) * scale;
                    const int rc = row >> 3;
                    const int slotT = (rc & 8) | ((rc & 7) ^ (col & 7));
                    smem[col * 128 + slotT * 8 + (row & 7)] = __float2bfloat16(v);
                }
        __syncthreads();
#pragma unroll
        for (int k = 0; k < 8; ++k) {
            const int flat = k * 256 + tid;
            const int seg  = flat >> 6, ln = flat & 63;
            const int kwl  = seg >> 2, g2l = seg & 3;
            const int dl   = g2l * 32 + (ln & 31);
            const int lc   = kwl * 2 + (ln >> 5);
            const int slotT = (lc & 8) | ((lc & 7) ^ (dl & 7));
            const f32x4 val = *(const f32x4*)(smem + dl * 128 + slotT * 8);
            const long addr = ((long)(nh * 64 + lt * 8 + kwl) * 8 + (d0 >> 5) + g2l) * 512 + ln * 8;
            *(f32x4*)(outV + addr) = val;
        }
    }
}

// ---------------------------------------------------------------------------
// Generic NT bf16 GEMM (kept for g4 only). 128x128 tile, BK=64, m97+R4 structure.
// mode 3: C=f32, acc + bias[row]
// mode 4: split-K atomic: atomicAdd(C, acc + (zh==0 ? bias[row] : 0))
// mode 5: split-K NON-atomic: plain store of acc to per-zh partial buffer
//         (bias applied later in reduce_out). B scaled by
//         1/Zp[zn*8 + zh*hperz + kt/4] during staging (hperz = 8/H).
__global__ __launch_bounds__(256)
void gemm_nt(const bf16* __restrict__ A, const bf16* __restrict__ B, void* __restrict__ Cvoid,
             int M, int N, int K, int lda, int ldb, int ldc,
             long asn, long ash, long bsn, long bsh, long csn, long csh,
             int H, int mode, const float* __restrict__ bias, const float* __restrict__ Zp,
             float scale)
{
    __shared__ __align__(16) bf16 smem[17408];
    bf16* Alds = smem;
    bf16* Blds = smem + 8192;

    const int tid  = threadIdx.x;
    const int wave = tid >> 6;
    const int lane = tid & 63;
    const int z  = blockIdx.z;
    const int zn = z / H, zh = z % H;
    const int hperz = 8 / H;

    const bf16* Ab = A + zn * asn + zh * ash;
    const bf16* Bb = B + zn * bsn + zh * bsh;

    const long tM = (long)blockIdx.y * 128;
    const long tN = (long)blockIdx.x * 128;

    const int wr   = (wave >> 1) * 64;
    const int wc   = (wave & 1) * 64;
    const int l15  = lane & 15;
    const int quad = lane >> 4;

    f32x4 acc[4][4] = {};

    const int kiters = K >> 6;
    const bool regB = (mode >= 4);

#pragma unroll
    for (int i = 0; i < 4; ++i) {
        const int flat = i * 256 + tid;
        const int row  = flat >> 3;
        const int kcs  = (flat & 7) ^ (row & 7);
        async_copy16(Ab + (tM + row) * (long)lda + kcs * 8,
                     (char*)Alds + (long)(i * 256 + wave * 64) * 16);
        if (!regB) {
            async_copy16(Bb + (tN + row) * (long)ldb + kcs * 8,
                         (char*)Blds + (long)(i * 256 + wave * 64) * 16);
        }
    }
    if (regB) {
        const float zi0 = 1.0f / Zp[zn * 8 + zh * hperz];
#pragma unroll
        for (int i = 0; i < 4; ++i) {
            const int flat = i * 256 + tid;
            const int row  = flat >> 3;
            const int kcs  = (flat & 7) ^ (row & 7);
            bf16x8 bv = *(const bf16x8*)(Bb + (tN + row) * (long)ldb + kcs * 8);
            *(bf16x8*)((char*)Blds + (long)flat * 16) = scale8(bv, zi0);
        }
    }

    bf16x8 pfA[4], pfB[4];
    for (int kt = 0; kt < kiters; ++kt) {
        __syncthreads();
        const bool has_next = (kt + 1 < kiters);
        float zin = 1.0f;
        if (has_next) {
            const long kof = (long)(kt + 1) * 64;
            if (regB) zin = 1.0f / Zp[zn * 8 + zh * hperz + ((kt + 1) >> 2)];
#pragma unroll
            for (int i = 0; i < 4; ++i) {
                const int flat = i * 256 + tid;
                const int row  = flat >> 3;
                const int kcs  = (flat & 7) ^ (row & 7);
                pfA[i] = *(const bf16x8*)(Ab + (tM + row) * (long)lda + kof + kcs * 8);
                pfB[i] = *(const bf16x8*)(Bb + (tN + row) * (long)ldb + kof + kcs * 8);
            }
        }
#pragma unroll
        for (int kk = 0; kk < 2; ++kk) {
            bf16x8 af[4], bfv[4];
#pragma unroll
            for (int i = 0; i < 4; ++i) {
                const int r = wr + i * 16 + l15;
                af[i] = *(const bf16x8*)(Alds + r * 64 + ((kk * 4 + quad) ^ (r & 7)) * 8);
            }
#pragma unroll
            for (int j = 0; j < 4; ++j) {
                const int r = wc + j * 16 + l15;
                bfv[j] = *(const bf16x8*)(Blds + r * 64 + ((kk * 4 + quad) ^ (r & 7)) * 8);
            }
#pragma unroll
            for (int i = 0; i < 4; ++i)
#pragma unroll
                for (int j = 0; j < 4; ++j)
                    acc[i][j] = __builtin_amdgcn_mfma_f32_16x16x32_bf16(af[i], bfv[j], acc[i][j], 0, 0, 0);
        }
        if (has_next) {
            __builtin_amdgcn_sched_barrier(0);
            __builtin_amdgcn_s_barrier();
            __builtin_amdgcn_sched_barrier(0);
#pragma unroll
            for (int i = 0; i < 4; ++i) {
                const int flat = i * 256 + tid;
                *(bf16x8*)((char*)Alds + (long)flat * 16) = pfA[i];
                *(bf16x8*)((char*)Blds + (long)flat * 16) = regB ? scale8(pfB[i], zin) : pfB[i];
            }
        }
    }

    float* C = (float*)Cvoid + zn * csn + zh * csh;
#pragma unroll
    for (int i = 0; i < 4; ++i)
#pragma unroll
        for (int j = 0; j < 4; ++j)
#pragma unroll
            for (int r = 0; r < 4; ++r) {
                const long row = tM + wr + i * 16 + quad * 4 + r;
                const long col = tN + wc + j * 16 + l15;
                if (mode == 5) {
                    C[row * (long)ldc + col] = acc[i][j][r];
                } else if (mode == 4) {
                    const float v = acc[i][j][r] + (zh == 0 ? bias[row] : 0.0f);
                    atomicAdd(&C[row * (long)ldc + col], v);
                } else {
                    C[row * (long)ldc + col] = acc[i][j][r] + bias[row];
                }
            }
}

// ---------------------------------------------------------------------------
// reduce_out (R20): out[n][c][l] = sum_{zh<4} Pt[zh][n][c][l] + b_out[c].
// Elementwise f32x4; 524288 vec4 elements; 40 MB traffic (~7us HBM-bound).
__global__ __launch_bounds__(256)
void reduce_out(const float* __restrict__ Pt, const float* __restrict__ bias,
                float* __restrict__ out)
{
    const int idx = blockIdx.x * 256 + threadIdx.x;       // [0, 524288)
    const int c   = (idx >> 8) & 255;                     // (idx*4 >> 10) & 255
    f32x4 s = ((const f32x4*)Pt)[idx];
    s += ((const f32x4*)(Pt + 2097152))[idx];
    s += ((const f32x4*)(Pt + 4194304))[idx];
    s += ((const f32x4*)(Pt + 6291456))[idx];
    const float b = bias[c];
    s[0] += b; s[1] += b; s[2] += b; s[3] += b;
    ((f32x4*)out)[idx] = s;
}

// ---------------------------------------------------------------------------
// Fused attention v6 (R11 schedule, verbatim). Block = (64-key m-tile, nh); grid 1024.
// Per lt: vf loads, QK MFMAs, exp+P store, __syncthreads, Qc(lt+1) prefetch, PV.
// DO NOT reorder the global loads relative to the barrier (R12-R14: +30-40% dur).
__global__ __launch_bounds__(256, 2)
void attn_fused(const bf16* __restrict__ Qsw, const bf16* __restrict__ Ksw,
                const bf16* __restrict__ Vsw, bf16* __restrict__ out_tt,
                float* __restrict__ Z)
{
    __shared__ __align__(16) bf16 smem[16904];
    bf16* Ps  = smem;
    float* Zs = (float*)(smem + 16896);

    const int tid  = threadIdx.x;
    const int wave = tid >> 6, lane = tid & 63;
    const int l31  = lane & 31, hw = lane >> 5;

    const int b   = blockIdx.x;
    const int xcd = b & 7, s = b >> 3;
    const int nh  = xcd * 8 + (s >> 4);
    const int mt  = s & 15;
    const int n   = nh >> 3, h = nh & 7;
    const long m0 = (long)mt * 64;

    const int wl = wave & 1, wm = wave >> 1;

    bf16x8 Kf[16];
    {
        const bf16* kb = Ksw + ((long)(nh * 32 + mt * 2 + wm) * 16) * 512 + lane * 8;
#pragma unroll
        for (int w = 0; w < 16; ++w)
            Kf[w] = *(const bf16x8*)(kb + w * 512);
    }
    bf16x8 Qc[16];
    {
        const bf16* qb = Qsw + ((long)(nh * 32 + wl) * 16) * 512 + lane * 8;
#pragma unroll
        for (int w = 0; w < 16; ++w)
            Qc[w] = *(const bf16x8*)(qb + w * 512);
    }

    f32x16 accO[2][2] = {};
    float zsum = 0.0f;

    for (int lt = 0; lt < 16; ++lt) {
        bf16x8 vf[4][2];
#pragma unroll
        for (int kw = 0; kw < 4; ++kw)
#pragma unroll
            for (int dt = 0; dt < 2; ++dt)
                vf[kw][dt] = *(const bf16x8*)(
                    Vsw + ((long)(nh * 64 + lt * 4 + kw) * 8 + wave * 2 + dt) * 512 + lane * 8);

        f32x16 a0 = {}, a1 = {};
#pragma unroll
        for (int w = 0; w < 16; w += 2) {
            a0 = __builtin_amdgcn_mfma_f32_32x32x16_bf16(Qc[w], Kf[w], a0, 0, 0, 0);
            a1 = __builtin_amdgcn_mfma_f32_32x32x16_bf16(Qc[w + 1], Kf[w + 1], a1, 0, 0, 0);
        }

        bf16* Pb = Ps + (lt & 1) * 6144;
#pragma unroll
        for (int g = 0; g < 4; ++g) {
            bf16x4 pk;
#pragma unroll
            for (int e = 0; e < 4; ++e) {
                const float v = __expf(a0[g * 4 + e] + a1[g * 4 + e]);
                zsum += v;
                pk[e] = (__bf16)v;
            }
            const int l  = wl * 32 + 4 * hw + 8 * g;
            const int kw = l >> 4, off = l & 15;
            *(bf16x4*)(Pb + kw * 1536 + (wm * 32 + l31) * 24 + off) = pk;
        }

        __syncthreads();

        if (lt < 15) {
            const bf16* qn = Qsw + ((long)(nh * 32 + (lt + 1) * 2 + wl) * 16) * 512 + lane * 8;
#pragma unroll
            for (int w = 0; w < 16; ++w)
                Qc[w] = *(const bf16x8*)(qn + w * 512);
        }

#pragma unroll
        for (int kw = 0; kw < 4; ++kw) {
            bf16x8 pf[2];
#pragma unroll
            for (int mh = 0; mh < 2; ++mh)
                pf[mh] = *(const bf16x8*)(Pb + kw * 1536 + (mh * 32 + l31) * 24 + hw * 8);
#pragma unroll
            for (int mh = 0; mh < 2; ++mh)
#pragma unroll
                for (int dt = 0; dt < 2; ++dt)
                    accO[mh][dt] = __builtin_amdgcn_mfma_f32_32x32x16_bf16(
                        pf[mh], vf[kw][dt], accO[mh][dt], 0, 0, 0);
        }
    }

    __syncthreads();

#pragma unroll
    for (int o = 32; o > 0; o >>= 1) zsum += __shfl_down(zsum, o);
    if (lane == 0) Zs[wave] = zsum;

    bf16* Cs = smem;
#pragma unroll
    for (int mh = 0; mh < 2; ++mh)
#pragma unroll
        for (int dt = 0; dt < 2; ++dt)
#pragma unroll
            for (int r = 0; r < 16; ++r) {
                const int m = mh * 32 + (r & 3) + 8 * (r >> 2) + 4 * hw;
                const int d = wave * 64 + dt * 32 + l31;
                Cs[m * 264 + d] = __float2bfloat16(accO[mh][dt][r]);
            }
    __syncthreads();
    if (tid == 0) atomicAdd(Z + nh, (Zs[0] + Zs[1]) + (Zs[2] + Zs[3]));

    bf16* Ob = out_tt + (long)n * 2097152 + m0 * 2048 + h * 256;
#pragma unroll
    for (int k = 0; k < 8; ++k) {
        const int flat = k * 256 + tid;
        const int row  = flat >> 5;
        const int c    = flat & 31;
        const f32x4 val = *(const f32x4*)((const char*)Cs + row * 528 + c * 16);
        *(f32x4*)((char*)(Ob + (long)row * 2048) + c * 16) = val;
    }
}

// ---------------------------------------------------------------------------
// prep_all (R21): fused prep. Blocks [0,512): x transpose -> Axw fragment layout
// (64x64 LDS tiles). Blocks [512,2560): w_in -> Wsw fragment-swizzle, w_out ->
// linear bf16, Z zeroing. One launch instead of two.
__global__ void prep_all(const float* __restrict__ x, const float* __restrict__ w_in,
                         const float* __restrict__ w_out, bf16* __restrict__ Axw,
                         bf16* __restrict__ Wsw, bf16* __restrict__ w_out_b,
                         float* __restrict__ Z)
{
    __shared__ float tile[64][65];
    const int t = threadIdx.x;

    if (blockIdx.x < 512) {
        // ---- prep_xt ----
        const int bid = blockIdx.x;
        const int n = bid >> 6;
        const int b = bid & 63;
        const int ct = b & 3, lt = b >> 2;
        const float* xp = x + (long)n * 256 * 1024;
#pragma unroll
        for (int i = 0; i < 16; ++i) {
            const int flat = i * 256 + t;
            const int cl = flat >> 6, ll = flat & 63;
            tile[cl][ll] = xp[(long)(ct * 64 + cl) * 1024 + lt * 64 + ll];
        }
        __syncthreads();
#pragma unroll
        for (int i = 0; i < 16; ++i) {
            const int flat = i * 256 + t;
            const int lr = flat >> 6, cr = flat & 63;
            const int l = lt * 64 + lr, c = ct * 64 + cr;
            const long addr = ((long)((n * 32 + (l >> 5)) * 16 + (c >> 4))) * 512
                            + ((l & 31) + 32 * ((c >> 3) & 1)) * 8 + (c & 7);
            Axw[addr] = __float2bfloat16(tile[cr][lr]);
        }
    } else {
        // ---- prep_convert ----
        const int cb = blockIdx.x - 512;                  // [0, 2048)
        const long gid = (long)cb * 256 + t;
        if (cb == 0 && t < 64) Z[t] = 0.0f;
        const long n1 = 6144L * 256;
        const long n2 = 256L * 2048;
        const long stride = 2048L * 256;
        for (long i = gid; i < n1; i += stride) {
            const int o = (int)(i >> 8), c = (int)(i & 255);
            const long addr = ((long)((o >> 5) * 16 + (c >> 4))) * 512
                            + ((o & 31) + 32 * ((c >> 3) & 1)) * 8 + (c & 7);
            Wsw[addr] = __float2bfloat16(w_in[i]);
        }
        for (long i = gid; i < n2; i += stride) w_out_b[i] = __float2bfloat16(w_out[i]);
    }
}

extern "C" void kernel_launch(void* const* d_in, const int* in_sizes, int n_in,
                              void* d_out, int out_size, void* d_ws, size_t ws_size,
                              hipStream_t stream)
{
    const float* x     = (const float*)d_in[0];
    const float* w_in  = (const float*)d_in[1];
    const float* b_in  = (const float*)d_in[2];
    const float* w_out = (const float*)d_in[3];
    const float* b_out = (const float*)d_in[4];
    float* out = (float*)d_out;

    const float SCALE = 0.10416666666666667f;     // 1/16 * sqrt(6400/2304) = 5/48

    char* p = (char*)d_ws;
    bf16* Qsw     = (bf16*)p;  p += 33554432;     // fragment-swizzled Q
    bf16* Ksw     = (bf16*)p;  p += 33554432;     // fragment-swizzled K
    bf16* Vsw     = (bf16*)p;  p += 33554432;     // fragment-swizzled V (transposed)
    bf16* out_tt  = (bf16*)p;  p += 33554432;     // (8, 1024, 2048) bf16 (unnormalized)
    bf16* Axw     = (bf16*)p;  p += 4194304;      // x_t fragment layout
    bf16* Wsw     = (bf16*)p;  p += 3145728;      // w_in fragment layout
    bf16* w_out_b = (bf16*)p;  p += 1048576;      // (256, 2048) bf16 linear
    float* Z      = (float*)p; p += 256;          // 64 softmax denominators
    float* Pt     = (float*)p; p += 33554432;     // 4 x (8,256,1024) f32 split-K partials

    // fused preps: xt blocks [0,512) + convert blocks [512,2560).
    prep_all<<<2560, 256, 0, stream>>>(x, w_in, w_out, Axw, Wsw, w_out_b, Z);

    // g1: fragment-direct projection, 3072 blocks (8n x 8ht x 6part x 8lt).
    proj_qkv<<<3072, 256, 0, stream>>>(Axw, Wsw, b_in, SCALE, Qsw, Ksw, Vsw);

    // fused attention (1D grid, XCD-swizzled)
    attn_fused<<<1024, 256, 0, stream>>>(Qsw, Ksw, Vsw, out_tt, Z);

    // g4: split-K=4 NON-atomic (R20). z = n*4 + zh, K=512/chunk, kiters=8,
    // 512 blocks (2 blocks/CU). Partials: Pt[zh][n][256][1024] f32.
    gemm_nt<<<dim3(8, 2, 32), 256, 0, stream>>>(
        w_out_b, out_tt, Pt,
        256, 1024, 512, 2048, 2048, 1024,
        0, 512, 1024L * 2048, 512, 262144, 2097152,
        4, 5, b_out, Z, 1.0f);

    // sum 4 partials + bias -> out (524288 f32x4, 2048 blocks).
    reduce_out<<<2048, 256, 0, stream>>>(Pt, b_out, out);
}